// Round 1
// 392.603 us; speedup vs baseline: 1.0059x; 1.0059x over previous
//
#include <hip/hip_runtime.h>
#include <hip/hip_bf16.h>

#define F_IN 256
#define HID  64
#define CLS  40
#define EPS  1e-8f
#define XS_STRIDE 264   // halfwords per LDS x-tile row: 2-way max bank aliasing (free)
#define DEG_STRIDE 32   // ints per degree counter: 128B apart -> no same-line atomic conflicts
#define CONV_ILP 4      // edges per thread in convert_kernel

typedef unsigned short ushort_t;
typedef unsigned int   uint_t;
typedef __attribute__((ext_vector_type(8))) short bf16x8;
typedef __attribute__((ext_vector_type(4))) float f32x4;

__device__ __forceinline__ float bf2f(ushort_t u) {
    union { uint_t i; float f; } v; v.i = ((uint_t)u) << 16; return v.f;
}
__device__ __forceinline__ ushort_t f2bf(float f) {
    union { float f; uint_t i; } v; v.f = f;
    uint_t r = v.i + 0x7fff + ((v.i >> 16) & 1);          // RNE
    return (ushort_t)(r >> 16);
}
__device__ __forceinline__ float blo(uint_t p) {
    union { uint_t i; float f; } v; v.i = p << 16; return v.f;
}
__device__ __forceinline__ float bhi(uint_t p) {
    union { uint_t i; float f; } v; v.i = p & 0xffff0000u; return v.f;
}
__device__ __forceinline__ float dot_u4(uint4 a, uint4 b) {
    return blo(a.x) * blo(b.x) + bhi(a.x) * bhi(b.x)
         + blo(a.y) * blo(b.y) + bhi(a.y) * bhi(b.y)
         + blo(a.z) * blo(b.z) + bhi(a.z) * bhi(b.z)
         + blo(a.w) * blo(b.w) + bhi(a.w) * bhi(b.w);
}

// -------------------- dtype detection (int64 vs int32 edge_index) -----------
__global__ void detect_kernel(const int* __restrict__ raw, int* __restrict__ flag) {
    int c = threadIdx.x;                  // one wave
    int w = raw[2 * c + 1];               // odd int32 words
    unsigned long long b = __ballot(w != 0);
    if (c == 0) *flag = (b == 0ULL) ? 1 : 0;   // all zero -> int64 layout
}

__global__ void init_deg_kernel(int* __restrict__ deg, int n) {
    int v = blockIdx.x * blockDim.x + threadIdx.x;
    if (v < n * DEG_STRIDE) deg[v] = 0;   // clear padded counter array
}

// ---- convert: pack (dst<<16)|src + degree atomic whose RETURN is the edge's
// rank among same-dst edges -> later CSR placement needs no second atomic pass.
// ILP=4 edges/thread: 4 independent atomics in flight; padded counters kill
// same-sector serialization in TCC.
__global__ void convert_kernel(const void* __restrict__ raw, const int* __restrict__ flag,
                               uint_t* __restrict__ pair, int* __restrict__ deg,
                               ushort_t* __restrict__ rank16, int E) {
    int t = blockIdx.x * blockDim.x + threadIdx.x;
    int e0 = t * CONV_ILP;
    if (e0 >= E) return;
    int cnt = E - e0;
    if (cnt > CONV_ILP) cnt = CONV_ILP;

    uint_t s[CONV_ILP], d[CONV_ILP];
    if (*flag) {
        const long long* r = (const long long*)raw;
        if (cnt == CONV_ILP && ((E & 1) == 0)) {           // 16B-aligned vector path
            ulonglong2 a0 = *(const ulonglong2*)(r + e0);
            ulonglong2 a1 = *(const ulonglong2*)(r + e0 + 2);
            ulonglong2 b0 = *(const ulonglong2*)(r + E + e0);
            ulonglong2 b1 = *(const ulonglong2*)(r + E + e0 + 2);
            s[0] = (uint_t)a0.x; s[1] = (uint_t)a0.y; s[2] = (uint_t)a1.x; s[3] = (uint_t)a1.y;
            d[0] = (uint_t)b0.x; d[1] = (uint_t)b0.y; d[2] = (uint_t)b1.x; d[3] = (uint_t)b1.y;
        } else {
            for (int k = 0; k < cnt; ++k) { s[k] = (uint_t)r[e0 + k]; d[k] = (uint_t)r[E + e0 + k]; }
        }
    } else {
        const int* r = (const int*)raw;
        if (cnt == CONV_ILP && ((E & 3) == 0)) {           // 16B-aligned vector path
            int4 a = *(const int4*)(r + e0);
            int4 b = *(const int4*)(r + E + e0);
            s[0] = (uint_t)a.x; s[1] = (uint_t)a.y; s[2] = (uint_t)a.z; s[3] = (uint_t)a.w;
            d[0] = (uint_t)b.x; d[1] = (uint_t)b.y; d[2] = (uint_t)b.z; d[3] = (uint_t)b.w;
        } else {
            for (int k = 0; k < cnt; ++k) { s[k] = (uint_t)r[e0 + k]; d[k] = (uint_t)r[E + e0 + k]; }
        }
    }

    int rk[CONV_ILP];
    #pragma unroll
    for (int k = 0; k < CONV_ILP; ++k)
        if (k < cnt) rk[k] = atomicAdd(&deg[d[k] * DEG_STRIDE], 1);   // 4 independent RMWs

    if (cnt == CONV_ILP) {
        uint4 p;
        p.x = (d[0] << 16) | s[0];
        p.y = (d[1] << 16) | s[1];
        p.z = (d[2] << 16) | s[2];
        p.w = (d[3] << 16) | s[3];
        *(uint4*)(pair + e0) = p;                          // 16B aligned (e0 % 4 == 0)
        ushort4 rr;
        rr.x = (ushort_t)rk[0]; rr.y = (ushort_t)rk[1];
        rr.z = (ushort_t)rk[2]; rr.w = (ushort_t)rk[3];
        *(ushort4*)(rank16 + e0) = rr;                     // 8B aligned
    } else {
        for (int k = 0; k < cnt; ++k) {
            pair[e0 + k]   = (d[k] << 16) | s[k];
            rank16[e0 + k] = (ushort_t)rk[k];
        }
    }
}

// ---- W1 -> bf16, pre-swizzled into MFMA B-fragment order -------------------
// frag elem j of (nt, kk, lane): W1[kk*32 + (lane>>4)*8 + j][nt*16 + (lane&15)]
// stored contiguously at W1s[(((nt*8)+kk)*64 + lane)*8 + j]
__global__ void convert_w1_kernel(const float* __restrict__ W1, ushort_t* __restrict__ W1s) {
    int t = blockIdx.x * blockDim.x + threadIdx.x;   // 2048 triples
    if (t >= 4 * 8 * 64) return;
    int lane = t & 63;
    int kk   = (t >> 6) & 7;
    int nt   = t >> 9;
    int col  = nt * 16 + (lane & 15);
    int k0   = kk * 32 + (lane >> 4) * 8;
    ushort_t v[8];
    #pragma unroll
    for (int j = 0; j < 8; ++j) v[j] = f2bf(W1[(size_t)(k0 + j) * HID + col]);
    uint4 p;
    p.x = (uint_t)v[0] | ((uint_t)v[1] << 16);
    p.y = (uint_t)v[2] | ((uint_t)v[3] << 16);
    p.z = (uint_t)v[4] | ((uint_t)v[5] << 16);
    p.w = (uint_t)v[6] | ((uint_t)v[7] << 16);
    *(uint4*)(W1s + (size_t)t * 8) = p;
}

// ---------- multi-block exclusive scan of edge-counts -> rowptr -------------
// phase 1: block-local exclusive scan, block totals to bsum; also dinv
__global__ void scan1_kernel(const int* __restrict__ deg, int* __restrict__ rowptr,
                             int* __restrict__ bsum, float* __restrict__ dinv, int n) {
    __shared__ int s[256];
    int tid = threadIdx.x;
    int i = blockIdx.x * 256 + tid;
    int v = (i < n) ? deg[(size_t)i * DEG_STRIDE] : 0;   // padded counter read
    if (i < n) dinv[i] = rsqrtf((float)(v + 1));   // +1 self-loop
    int x = v;
    s[tid] = x;
    __syncthreads();
    #pragma unroll
    for (int o = 1; o < 256; o <<= 1) {
        int t = (tid >= o) ? s[tid - o] : 0;
        __syncthreads();
        x += t;
        s[tid] = x;
        __syncthreads();
    }
    if (i < n) rowptr[i] = x - v;                  // block-local exclusive
    if (tid == 255) bsum[blockIdx.x] = x;          // block total
}

// phase 2: exclusive scan of block sums (nb <= 256), single block
__global__ void scan2_kernel(int* __restrict__ bsum, int nb) {
    __shared__ int s[256];
    int tid = threadIdx.x;
    int v = (tid < nb) ? bsum[tid] : 0;
    int x = v;
    s[tid] = x;
    __syncthreads();
    #pragma unroll
    for (int o = 1; o < 256; o <<= 1) {
        int t = (tid >= o) ? s[tid - o] : 0;
        __syncthreads();
        x += t;
        s[tid] = x;
        __syncthreads();
    }
    if (tid < nb) bsum[tid] = x - v;               // exclusive block offsets
}

// phase 3: add block offsets; rowptr[n] = E
__global__ void scan3_kernel(int* __restrict__ rowptr, const int* __restrict__ bsum,
                             int n, int E) {
    int i = blockIdx.x * 256 + threadIdx.x;
    if (i < n) rowptr[i] += bsum[blockIdx.x];
    if (i == 0) rowptr[n] = E;                     // sum of edge counts == E
}

// ---- place: csr[rowptr[dst] + rank] = src — pure stores, no atomics --------
__global__ void place_kernel(const uint_t* __restrict__ pair,
                             const ushort_t* __restrict__ rank16,
                             const int* __restrict__ rowptr,
                             ushort_t* __restrict__ csr, int E) {
    int e = blockIdx.x * blockDim.x + threadIdx.x;
    if (e >= E) return;
    uint_t u = pair[e];
    int d = (int)(u >> 16);
    int pos = rowptr[d] + (int)rank16[e];
    csr[pos] = (ushort_t)(u & 0xffffu);
}

// ------- layer 1 GEMM on MFMA: xws = bf16((x @ W1) * dinv[node]) ------------
// block = 256 threads = 4 waves; 16 nodes/block; wave w owns N-tile w (16 ch)
__global__ void gemm1_mfma_kernel(const float* __restrict__ x,
                                  const ushort_t* __restrict__ W1s,
                                  const float* __restrict__ dinv,
                                  ushort_t* __restrict__ xws, int n) {
    __shared__ ushort_t xs[16 * XS_STRIDE];           // 8448 B bf16 x-tile
    int node0 = blockIdx.x * 16;
    int tid = threadIdx.x;
    for (int i = tid; i < 16 * 64; i += 256) {        // stage x tile -> bf16 LDS
        int r  = i >> 6;
        int c4 = (i & 63) << 2;
        int node = node0 + r;
        float4 v = (node < n) ? *(const float4*)(x + (size_t)node * F_IN + c4)
                              : make_float4(0.f, 0.f, 0.f, 0.f);
        ushort4 b;
        b.x = f2bf(v.x); b.y = f2bf(v.y); b.z = f2bf(v.z); b.w = f2bf(v.w);
        *(ushort4*)(&xs[r * XS_STRIDE + c4]) = b;     // 8B-aligned ds_write_b64
    }
    __syncthreads();
    int wave = tid >> 6;                              // N-tile index 0..3
    int lane = tid & 63;
    int m    = lane & 15;
    int q    = lane >> 4;
    f32x4 acc = {0.f, 0.f, 0.f, 0.f};
    #pragma unroll
    for (int kk = 0; kk < 8; ++kk) {                  // K = 8 x 32
        bf16x8 a = *(const bf16x8*)(&xs[m * XS_STRIDE + kk * 32 + q * 8]);
        bf16x8 b = *(const bf16x8*)(W1s + (((size_t)wave * 8 + kk) * 64 + lane) * 8);
        acc = __builtin_amdgcn_mfma_f32_16x16x32_bf16(a, b, acc, 0, 0, 0);
    }
    int ch = wave * 16 + m;                           // C/D: col=lane&15, row=q*4+r
    #pragma unroll
    for (int r = 0; r < 4; ++r) {
        int node = node0 + q * 4 + r;
        if (node < n)
            xws[(size_t)node * HID + ch] = f2bf(acc[r] * dinv[node]);
    }
}

// ---- fused: gather1 (h = relu(dinv*(sum)+b1)) + gemm2 (hws = h@W2 * dinv) --
// one wave per node; 4 waves/block; h row staged in LDS for the 64->40 matmul
__global__ void gather1_gemm2_kernel(const int* __restrict__ rowptr,
                                     const ushort_t* __restrict__ csr,
                                     const ushort_t* __restrict__ xws,
                                     const float* __restrict__ dinv,
                                     const float* __restrict__ b1,
                                     const float* __restrict__ W2,
                                     ushort_t* __restrict__ hws, int n) {
    __shared__ float hbuf[4][72];
    int wave = threadIdx.x >> 6;
    int c    = threadIdx.x & 63;
    int wv   = (blockIdx.x * blockDim.x + threadIdx.x) >> 6;
    bool active = wv < n;
    int beg = 0, endp = 0;
    float acc = 0.f, di = 0.f;
    if (active) {
        beg = rowptr[wv]; endp = rowptr[wv + 1];
        di  = dinv[wv];
        acc = bf2f(xws[(size_t)wv * HID + c]);        // self-loop term
    }
    int j = beg;
    for (; j + 8 <= endp; j += 8) {                   // 8 outstanding row loads
        int s0 = csr[j],     s1 = csr[j + 1], s2 = csr[j + 2], s3 = csr[j + 3];
        int s4 = csr[j + 4], s5 = csr[j + 5], s6 = csr[j + 6], s7 = csr[j + 7];
        float v0 = bf2f(xws[(size_t)s0 * HID + c]);
        float v1 = bf2f(xws[(size_t)s1 * HID + c]);
        float v2 = bf2f(xws[(size_t)s2 * HID + c]);
        float v3 = bf2f(xws[(size_t)s3 * HID + c]);
        float v4 = bf2f(xws[(size_t)s4 * HID + c]);
        float v5 = bf2f(xws[(size_t)s5 * HID + c]);
        float v6 = bf2f(xws[(size_t)s6 * HID + c]);
        float v7 = bf2f(xws[(size_t)s7 * HID + c]);
        acc += ((v0 + v1) + (v2 + v3)) + ((v4 + v5) + (v6 + v7));
    }
    for (; j < endp; ++j) acc += bf2f(xws[(size_t)csr[j] * HID + c]);
    float hv = active ? fmaxf(acc * di + b1[c], 0.f) : 0.f;
    hbuf[wave][c] = hv;
    __syncthreads();
    if (active && c < CLS) {
        float o = 0.f;
        const float* hr = hbuf[wave];
        #pragma unroll 8
        for (int k = 0; k < HID; ++k) o += hr[k] * W2[k * CLS + c];
        hws[(size_t)wv * CLS + c] = f2bf(o * di);
    }
}

// ---------- layer 2 gather fused with finalize ------------------------------
__global__ void gather2_fin_kernel(const int* __restrict__ rowptr,
                                   const ushort_t* __restrict__ csr,
                                   const ushort_t* __restrict__ hws,
                                   const float* __restrict__ dinv,
                                   const float* __restrict__ b2,
                                   float* __restrict__ xout, float* __restrict__ lsm,
                                   float* __restrict__ sm, ushort_t* __restrict__ xoutb,
                                   float* __restrict__ rnorm, int n) {
    int wv = (blockIdx.x * blockDim.x + threadIdx.x) >> 6;
    int c  = threadIdx.x & 63;
    if (wv >= n) return;
    int beg = rowptr[wv], endp = rowptr[wv + 1];
    bool act = c < CLS;
    float acc = 0.f;
    if (act) acc = bf2f(hws[(size_t)wv * CLS + c]);   // self-loop term
    int j = beg;
    for (; j + 8 <= endp; j += 8) {
        int s0 = csr[j],     s1 = csr[j + 1], s2 = csr[j + 2], s3 = csr[j + 3];
        int s4 = csr[j + 4], s5 = csr[j + 5], s6 = csr[j + 6], s7 = csr[j + 7];
        if (act) {
            float v0 = bf2f(hws[(size_t)s0 * CLS + c]);
            float v1 = bf2f(hws[(size_t)s1 * CLS + c]);
            float v2 = bf2f(hws[(size_t)s2 * CLS + c]);
            float v3 = bf2f(hws[(size_t)s3 * CLS + c]);
            float v4 = bf2f(hws[(size_t)s4 * CLS + c]);
            float v5 = bf2f(hws[(size_t)s5 * CLS + c]);
            float v6 = bf2f(hws[(size_t)s6 * CLS + c]);
            float v7 = bf2f(hws[(size_t)s7 * CLS + c]);
            acc += ((v0 + v1) + (v2 + v3)) + ((v4 + v5) + (v6 + v7));
        }
    }
    for (; j < endp; ++j) {
        int s = csr[j];
        if (act) acc += bf2f(hws[(size_t)s * CLS + c]);
    }
    float raw = 0.f;
    if (act) raw = acc * dinv[wv] + b2[c];
    float m = act ? raw : -3.0e38f;
    #pragma unroll
    for (int o = 32; o > 0; o >>= 1) m = fmaxf(m, __shfl_xor(m, o));
    float ex = act ? __expf(raw - m) : 0.f;
    float ssum = ex;
    #pragma unroll
    for (int o = 32; o > 0; o >>= 1) ssum += __shfl_xor(ssum, o);
    float sq = act ? raw * raw : 0.f;
    #pragma unroll
    for (int o = 32; o > 0; o >>= 1) sq += __shfl_xor(sq, o);
    size_t base = (size_t)wv * CLS + c;
    if (act) {
        xout[base]  = raw;
        float lse = m + __logf(ssum);
        lsm[base]   = raw - lse;
        sm[base]    = ex / ssum;
        xoutb[base] = f2bf(raw);
    }
    if (c == 0) rnorm[wv] = 1.0f / fmaxf(sqrtf(sq), EPS);
}

// ------------- per-edge cosine dissimilarity + gnn_edge ---------------------
// 80B row = 5 x uint4 loads per operand (full 40 bf16 channels)
__global__ void edge_kernel(const uint_t* __restrict__ pair,
                            const float* __restrict__ ew, const ushort_t* __restrict__ xoutb,
                            const float* __restrict__ rnorm,
                            float* __restrict__ cos_out, float* __restrict__ gnn_out, int E) {
    int e = blockIdx.x * blockDim.x + threadIdx.x;
    if (e >= E) return;
    uint_t u = pair[e];
    int s = (int)(u & 0xffffu);
    int d = (int)(u >> 16);
    const uint4* a4 = (const uint4*)(xoutb + (size_t)s * CLS);   // rows are 80B = 5*16B
    const uint4* b4 = (const uint4*)(xoutb + (size_t)d * CLS);
    uint4 a0 = a4[0], a1 = a4[1], a2 = a4[2], a3 = a4[3], a4v = a4[4];
    uint4 b0 = b4[0], b1 = b4[1], b2 = b4[2], b3 = b4[3], b4v = b4[4];
    float rs = rnorm[s], rd = rnorm[d];
    float dot = dot_u4(a0, b0) + dot_u4(a1, b1) + dot_u4(a2, b2)
              + dot_u4(a3, b3) + dot_u4(a4v, b4v);
    cos_out[e] = 1.0f - dot * rs * rd;
    gnn_out[e] = (ew[e] > 0.5f) ? 1.0f : -1.0f;
}

// ---------------------------------------------------------------------------
extern "C" void kernel_launch(void* const* d_in, const int* in_sizes, int n_in,
                              void* d_out, int out_size, void* d_ws, size_t ws_size,
                              hipStream_t stream) {
    const float* x   = (const float*)d_in[0];
    const void*  ei  = d_in[1];
    const float* ew  = (const float*)d_in[2];
    const float* W1  = (const float*)d_in[3];
    const float* b1  = (const float*)d_in[4];
    const float* W2  = (const float*)d_in[5];
    const float* b2  = (const float*)d_in[6];

    const int n = in_sizes[0] / F_IN;        // 50000
    const int E = in_sizes[2];               // 1600000

    // output segments (return order)
    float* lsm  = (float*)d_out;                                   // [n*CLS]
    float* xout = lsm + (size_t)n * CLS;                           // [n*CLS]
    float* cosO = xout + (size_t)n * CLS;                          // [E]
    float* gnnO = cosO + E;                                        // [E]
    float* smO  = gnnO + E;                                        // [n*CLS]

    // workspace layout (256B aligned)
    char* w = (char*)d_ws;
    auto alloc = [&](size_t bytes) {
        char* p = w;
        w += (bytes + 255) & ~(size_t)255;
        return p;
    };
    uint_t*   pair   = (uint_t*)  alloc((size_t)E * 4);
    ushort_t* csr16  = (ushort_t*)alloc((size_t)E * 2);
    ushort_t* rank16 = (ushort_t*)alloc((size_t)E * 2);
    int*      deg    = (int*)     alloc((size_t)n * DEG_STRIDE * 4);   // padded: 128B/counter
    int*      rowptr = (int*)     alloc(((size_t)n + 1) * 4);
    float*    dinv   = (float*)   alloc((size_t)n * 4);
    ushort_t* xws    = (ushort_t*)alloc((size_t)n * HID * 2);
    ushort_t* hws    = (ushort_t*)alloc((size_t)n * CLS * 2);
    ushort_t* xoutb  = (ushort_t*)alloc((size_t)n * CLS * 2);
    float*    rnorm  = (float*)   alloc((size_t)n * 4);
    ushort_t* W1s    = (ushort_t*)alloc((size_t)4 * 8 * 64 * 8 * 2);   // 32 KB
    int*      bsum   = (int*)     alloc(256 * 4);
    int*      flag   = (int*)     alloc(64);

    const int nscan = (n + 255) / 256;       // 196 scan blocks (<= 256)
    const int nconv = ((E + CONV_ILP - 1) / CONV_ILP + 255) / 256;

    detect_kernel<<<1, 64, 0, stream>>>((const int*)ei, flag);
    convert_w1_kernel<<<8, 256, 0, stream>>>(W1, W1s);
    init_deg_kernel<<<((size_t)n * DEG_STRIDE + 255) / 256, 256, 0, stream>>>(deg, n);
    convert_kernel<<<nconv, 256, 0, stream>>>(ei, flag, pair, deg, rank16, E);
    scan1_kernel<<<nscan, 256, 0, stream>>>(deg, rowptr, bsum, dinv, n);
    scan2_kernel<<<1, 256, 0, stream>>>(bsum, nscan);
    scan3_kernel<<<nscan, 256, 0, stream>>>(rowptr, bsum, n, E);
    place_kernel<<<(E + 255) / 256, 256, 0, stream>>>(pair, rank16, rowptr, csr16, E);
    gemm1_mfma_kernel<<<(n + 15) / 16, 256, 0, stream>>>(x, W1s, dinv, xws, n);
    gather1_gemm2_kernel<<<((size_t)n * 64 + 255) / 256, 256, 0, stream>>>(rowptr, csr16, xws, dinv,
                                                                           b1, W2, hws, n);
    gather2_fin_kernel<<<((size_t)n * 64 + 255) / 256, 256, 0, stream>>>(rowptr, csr16, hws, dinv, b2,
                                                                         xout, lsm, smO, xoutb, rnorm, n);
    edge_kernel<<<(E + 255) / 256, 256, 0, stream>>>(pair, ew, xoutb, rnorm, cosO, gnnO, E);
}

// Round 4
// 387.944 us; speedup vs baseline: 1.0180x; 1.0120x over previous
//
#include <hip/hip_runtime.h>
#include <hip/hip_bf16.h>

#define F_IN 256
#define HID  64
#define CLS  40
#define EPS  1e-8f
#define XS_STRIDE 264   // halfwords per LDS x-tile row: 2-way max bank aliasing (free)
#define EPB  8192       // edges per block in hist/scatter passes (256 thr x 32)

typedef unsigned short ushort_t;
typedef unsigned int   uint_t;
typedef __attribute__((ext_vector_type(8))) short bf16x8;
typedef __attribute__((ext_vector_type(4))) float f32x4;

__device__ __forceinline__ float bf2f(ushort_t u) {
    union { uint_t i; float f; } v; v.i = ((uint_t)u) << 16; return v.f;
}
__device__ __forceinline__ ushort_t f2bf(float f) {
    union { float f; uint_t i; } v; v.f = f;
    uint_t r = v.i + 0x7fff + ((v.i >> 16) & 1);          // RNE
    return (ushort_t)(r >> 16);
}
__device__ __forceinline__ float blo(uint_t p) {
    union { uint_t i; float f; } v; v.i = p << 16; return v.f;
}
__device__ __forceinline__ float bhi(uint_t p) {
    union { uint_t i; float f; } v; v.i = p & 0xffff0000u; return v.f;
}
__device__ __forceinline__ float dot_u4(uint4 a, uint4 b) {
    return blo(a.x) * blo(b.x) + bhi(a.x) * bhi(b.x)
         + blo(a.y) * blo(b.y) + bhi(a.y) * bhi(b.y)
         + blo(a.z) * blo(b.z) + bhi(a.z) * bhi(b.z)
         + blo(a.w) * blo(b.w) + bhi(a.w) * bhi(b.w);
}

// -------------------- dtype detection (int64 vs int32 edge_index) -----------
__global__ void detect_kernel(const int* __restrict__ raw, int* __restrict__ flag) {
    int c = threadIdx.x;                  // one wave
    int w = raw[2 * c + 1];               // odd int32 words
    unsigned long long b = __ballot(w != 0);
    if (c == 0) *flag = (b == 0ULL) ? 1 : 0;   // all zero -> int64 layout
}

// ---- pass 1: pair packing + per-block bucket histogram (dst>>8) ------------
// NO global atomics anywhere in the CSR build: LDS histogram + scans instead.
__global__ void build_hist_kernel(const void* __restrict__ raw, const int* __restrict__ flag,
                                  uint_t* __restrict__ pair, int* __restrict__ ghist, int E) {
    __shared__ int lhist[256];
    int tid = threadIdx.x;
    lhist[tid] = 0;
    __syncthreads();
    int base = blockIdx.x * EPB;
    if (*flag) {
        const long long* r = (const long long*)raw;
        for (int it = 0; it < EPB / 1024; ++it) {        // 4 edges/thread/iter
            int e = base + (it * 256 + tid) * 4;
            if (e + 4 <= E) {
                ulonglong2 a0 = *(const ulonglong2*)(r + e);
                ulonglong2 a1 = *(const ulonglong2*)(r + e + 2);
                ulonglong2 b0 = *(const ulonglong2*)(r + E + e);
                ulonglong2 b1 = *(const ulonglong2*)(r + E + e + 2);
                uint_t d0 = (uint_t)b0.x, d1 = (uint_t)b0.y;
                uint_t d2 = (uint_t)b1.x, d3 = (uint_t)b1.y;
                uint4 p;
                p.x = (d0 << 16) | (uint_t)a0.x;
                p.y = (d1 << 16) | (uint_t)a0.y;
                p.z = (d2 << 16) | (uint_t)a1.x;
                p.w = (d3 << 16) | (uint_t)a1.y;
                *(uint4*)(pair + e) = p;
                atomicAdd(&lhist[d0 >> 8], 1);
                atomicAdd(&lhist[d1 >> 8], 1);
                atomicAdd(&lhist[d2 >> 8], 1);
                atomicAdd(&lhist[d3 >> 8], 1);
            } else {
                for (int k = 0; k < 4; ++k) {
                    int ee = e + k;
                    if (ee < E) {
                        uint_t s = (uint_t)r[ee];
                        uint_t d = (uint_t)r[E + ee];
                        pair[ee] = (d << 16) | s;
                        atomicAdd(&lhist[d >> 8], 1);
                    }
                }
            }
        }
    } else {
        const int* r = (const int*)raw;
        for (int it = 0; it < EPB / 1024; ++it) {        // 4 edges/thread/iter
            int e = base + (it * 256 + tid) * 4;
            if (e + 4 <= E) {
                int4 a = *(const int4*)(r + e);
                int4 b = *(const int4*)(r + E + e);
                uint_t d0 = (uint_t)b.x, d1 = (uint_t)b.y;
                uint_t d2 = (uint_t)b.z, d3 = (uint_t)b.w;
                uint4 p;
                p.x = (d0 << 16) | (uint_t)a.x;
                p.y = (d1 << 16) | (uint_t)a.y;
                p.z = (d2 << 16) | (uint_t)a.z;
                p.w = (d3 << 16) | (uint_t)a.w;
                *(uint4*)(pair + e) = p;
                atomicAdd(&lhist[d0 >> 8], 1);
                atomicAdd(&lhist[d1 >> 8], 1);
                atomicAdd(&lhist[d2 >> 8], 1);
                atomicAdd(&lhist[d3 >> 8], 1);
            } else {
                for (int k = 0; k < 4; ++k) {
                    int ee = e + k;
                    if (ee < E) {
                        uint_t s = (uint_t)r[ee];
                        uint_t d = (uint_t)r[E + ee];
                        pair[ee] = (d << 16) | s;
                        atomicAdd(&lhist[d >> 8], 1);
                    }
                }
            }
        }
    }
    __syncthreads();
    ghist[blockIdx.x * 256 + tid] = lhist[tid];
}

// ---- pass 2 (single block): column scan of ghist + bucket bases ------------
// thread k owns bucket k: serial scan over blocks, ghist[b][k] overwritten
// with block b's exclusive offset within bucket k; then scan bucket totals.
__global__ void scan_buckets_kernel(int* __restrict__ ghist, int* __restrict__ bbase,
                                    int NBLK) {
    __shared__ int s[256];
    int k = threadIdx.x;
    int run = 0;
    for (int b = 0; b < NBLK; ++b) {
        int v = ghist[b * 256 + k];
        ghist[b * 256 + k] = run;
        run += v;
    }
    int x = run;                               // bucket k total
    s[k] = x;
    __syncthreads();
    #pragma unroll
    for (int o = 1; o < 256; o <<= 1) {
        int t = (k >= o) ? s[k - o] : 0;
        __syncthreads();
        x += t;
        s[k] = x;
        __syncthreads();
    }
    bbase[k] = x - run;                        // exclusive bucket base
    if (k == 255) bbase[256] = x;              // == E
}

// ---- pass 3: scatter edges into bucket regions (LDS cursors only) ----------
// block b's targets in bucket k are the exclusive range [off(b,k), off(b,k)+cnt):
// 4B stores merge in write-back L2 -> ~no write amplification.
__global__ void scatter_buckets_kernel(const uint_t* __restrict__ pair,
                                       const int* __restrict__ ghist,
                                       const int* __restrict__ bbase,
                                       uint_t* __restrict__ bkt, int E) {
    __shared__ int cursor[256];
    int tid = threadIdx.x;
    cursor[tid] = ghist[blockIdx.x * 256 + tid] + bbase[tid];
    __syncthreads();
    int base = blockIdx.x * EPB;
    for (int it = 0; it < EPB / 256; ++it) {
        int e = base + it * 256 + tid;
        if (e < E) {
            uint_t u = pair[e];
            int pos = atomicAdd(&cursor[u >> 24], 1);   // LDS atomic, returns rank
            bkt[pos] = u;
        }
    }
}

// ---- pass 4: one block per bucket -> deg/rowptr/dinv + sorted csr16 --------
// bucket k holds ALL edges of nodes [k*256,(k+1)*256): LDS histogram over
// dst&255 IS the exact degree; LDS scan gives rowptr; LDS cursors place src.
// Bucket segment (~33 KB) is read twice from global; it is L2-resident after
// pass A, so the second read is ~free. Only 3 KB LDS -> no occupancy/LDS risk.
__global__ void bucket_csr_kernel(const uint_t* __restrict__ bkt,
                                  const int* __restrict__ bbase,
                                  ushort_t* __restrict__ csr, int* __restrict__ rowptr,
                                  float* __restrict__ dinv, int n, int E, int NBUCK) {
    __shared__ int lhist[256];
    __shared__ int lscan[256];
    __shared__ int cursor[256];
    int tid = threadIdx.x;
    int kb  = blockIdx.x;
    int base = bbase[kb];
    int cnt  = bbase[kb + 1] - base;
    lhist[tid] = 0;
    __syncthreads();
    for (int i = tid; i < cnt; i += 256) {            // pass A: exact degrees
        uint_t u = bkt[base + i];
        atomicAdd(&lhist[(u >> 16) & 255], 1);
    }
    __syncthreads();
    int v = lhist[tid];                        // degree of node kb*256+tid (no self-loop)
    int x = v;
    lscan[tid] = x;
    __syncthreads();
    #pragma unroll
    for (int o = 1; o < 256; o <<= 1) {
        int t = (tid >= o) ? lscan[tid - o] : 0;
        __syncthreads();
        x += t;
        lscan[tid] = x;
        __syncthreads();
    }
    int excl = x - v;                          // exclusive scan within bucket
    int node = kb * 256 + tid;
    if (node < n) {
        rowptr[node] = base + excl;
        dinv[node]   = rsqrtf((float)(v + 1)); // +1 self-loop
    }
    cursor[tid] = base + excl;
    if (kb == NBUCK - 1 && tid == 0) rowptr[n] = E;
    __syncthreads();
    for (int i = tid; i < cnt; i += 256) {            // pass B: place src
        uint_t u = bkt[base + i];                     // L2 hit (just touched)
        int pos = atomicAdd(&cursor[(u >> 16) & 255], 1);   // LDS atomic
        csr[pos] = (ushort_t)(u & 0xffffu);    // 2B scatter, block-local region
    }
}

// ---- W1 -> bf16, pre-swizzled into MFMA B-fragment order -------------------
// frag elem j of (nt, kk, lane): W1[kk*32 + (lane>>4)*8 + j][nt*16 + (lane&15)]
// stored contiguously at W1s[(((nt*8)+kk)*64 + lane)*8 + j]
__global__ void convert_w1_kernel(const float* __restrict__ W1, ushort_t* __restrict__ W1s) {
    int t = blockIdx.x * blockDim.x + threadIdx.x;   // 2048 triples
    if (t >= 4 * 8 * 64) return;
    int lane = t & 63;
    int kk   = (t >> 6) & 7;
    int nt   = t >> 9;
    int col  = nt * 16 + (lane & 15);
    int k0   = kk * 32 + (lane >> 4) * 8;
    ushort_t v[8];
    #pragma unroll
    for (int j = 0; j < 8; ++j) v[j] = f2bf(W1[(size_t)(k0 + j) * HID + col]);
    uint4 p;
    p.x = (uint_t)v[0] | ((uint_t)v[1] << 16);
    p.y = (uint_t)v[2] | ((uint_t)v[3] << 16);
    p.z = (uint_t)v[4] | ((uint_t)v[5] << 16);
    p.w = (uint_t)v[6] | ((uint_t)v[7] << 16);
    *(uint4*)(W1s + (size_t)t * 8) = p;
}

// ------- layer 1 GEMM on MFMA: xws = bf16((x @ W1) * dinv[node]) ------------
// block = 256 threads = 4 waves; 16 nodes/block; wave w owns N-tile w (16 ch)
__global__ void gemm1_mfma_kernel(const float* __restrict__ x,
                                  const ushort_t* __restrict__ W1s,
                                  const float* __restrict__ dinv,
                                  ushort_t* __restrict__ xws, int n) {
    __shared__ ushort_t xs[16 * XS_STRIDE];           // 8448 B bf16 x-tile
    int node0 = blockIdx.x * 16;
    int tid = threadIdx.x;
    for (int i = tid; i < 16 * 64; i += 256) {        // stage x tile -> bf16 LDS
        int r  = i >> 6;
        int c4 = (i & 63) << 2;
        int node = node0 + r;
        float4 v = (node < n) ? *(const float4*)(x + (size_t)node * F_IN + c4)
                              : make_float4(0.f, 0.f, 0.f, 0.f);
        ushort4 b;
        b.x = f2bf(v.x); b.y = f2bf(v.y); b.z = f2bf(v.z); b.w = f2bf(v.w);
        *(ushort4*)(&xs[r * XS_STRIDE + c4]) = b;     // 8B-aligned ds_write_b64
    }
    __syncthreads();
    int wave = tid >> 6;                              // N-tile index 0..3
    int lane = tid & 63;
    int m    = lane & 15;
    int q    = lane >> 4;
    f32x4 acc = {0.f, 0.f, 0.f, 0.f};
    #pragma unroll
    for (int kk = 0; kk < 8; ++kk) {                  // K = 8 x 32
        bf16x8 a = *(const bf16x8*)(&xs[m * XS_STRIDE + kk * 32 + q * 8]);
        bf16x8 b = *(const bf16x8*)(W1s + (((size_t)wave * 8 + kk) * 64 + lane) * 8);
        acc = __builtin_amdgcn_mfma_f32_16x16x32_bf16(a, b, acc, 0, 0, 0);
    }
    int ch = wave * 16 + m;                           // C/D: col=lane&15, row=q*4+r
    #pragma unroll
    for (int r = 0; r < 4; ++r) {
        int node = node0 + q * 4 + r;
        if (node < n)
            xws[(size_t)node * HID + ch] = f2bf(acc[r] * dinv[node]);
    }
}

// ---- fused: gather1 (h = relu(dinv*(sum)+b1)) + gemm2 (hws = h@W2 * dinv) --
// one wave per node; 4 waves/block; h row staged in LDS for the 64->40 matmul
__global__ void gather1_gemm2_kernel(const int* __restrict__ rowptr,
                                     const ushort_t* __restrict__ csr,
                                     const ushort_t* __restrict__ xws,
                                     const float* __restrict__ dinv,
                                     const float* __restrict__ b1,
                                     const float* __restrict__ W2,
                                     ushort_t* __restrict__ hws, int n) {
    __shared__ float hbuf[4][72];
    int wave = threadIdx.x >> 6;
    int c    = threadIdx.x & 63;
    int wv   = (blockIdx.x * blockDim.x + threadIdx.x) >> 6;
    bool active = wv < n;
    int beg = 0, endp = 0;
    float acc = 0.f, di = 0.f;
    if (active) {
        beg = rowptr[wv]; endp = rowptr[wv + 1];
        di  = dinv[wv];
        acc = bf2f(xws[(size_t)wv * HID + c]);        // self-loop term
    }
    int j = beg;
    for (; j + 8 <= endp; j += 8) {                   // 8 outstanding row loads
        int s0 = csr[j],     s1 = csr[j + 1], s2 = csr[j + 2], s3 = csr[j + 3];
        int s4 = csr[j + 4], s5 = csr[j + 5], s6 = csr[j + 6], s7 = csr[j + 7];
        float v0 = bf2f(xws[(size_t)s0 * HID + c]);
        float v1 = bf2f(xws[(size_t)s1 * HID + c]);
        float v2 = bf2f(xws[(size_t)s2 * HID + c]);
        float v3 = bf2f(xws[(size_t)s3 * HID + c]);
        float v4 = bf2f(xws[(size_t)s4 * HID + c]);
        float v5 = bf2f(xws[(size_t)s5 * HID + c]);
        float v6 = bf2f(xws[(size_t)s6 * HID + c]);
        float v7 = bf2f(xws[(size_t)s7 * HID + c]);
        acc += ((v0 + v1) + (v2 + v3)) + ((v4 + v5) + (v6 + v7));
    }
    for (; j < endp; ++j) acc += bf2f(xws[(size_t)csr[j] * HID + c]);
    float hv = active ? fmaxf(acc * di + b1[c], 0.f) : 0.f;
    hbuf[wave][c] = hv;
    __syncthreads();
    if (active && c < CLS) {
        float o = 0.f;
        const float* hr = hbuf[wave];
        #pragma unroll 8
        for (int k = 0; k < HID; ++k) o += hr[k] * W2[k * CLS + c];
        hws[(size_t)wv * CLS + c] = f2bf(o * di);
    }
}

// ---------- layer 2 gather fused with finalize ------------------------------
__global__ void gather2_fin_kernel(const int* __restrict__ rowptr,
                                   const ushort_t* __restrict__ csr,
                                   const ushort_t* __restrict__ hws,
                                   const float* __restrict__ dinv,
                                   const float* __restrict__ b2,
                                   float* __restrict__ xout, float* __restrict__ lsm,
                                   float* __restrict__ sm, ushort_t* __restrict__ xoutb,
                                   float* __restrict__ rnorm, int n) {
    int wv = (blockIdx.x * blockDim.x + threadIdx.x) >> 6;
    int c  = threadIdx.x & 63;
    if (wv >= n) return;
    int beg = rowptr[wv], endp = rowptr[wv + 1];
    bool act = c < CLS;
    float acc = 0.f;
    if (act) acc = bf2f(hws[(size_t)wv * CLS + c]);   // self-loop term
    int j = beg;
    for (; j + 8 <= endp; j += 8) {
        int s0 = csr[j],     s1 = csr[j + 1], s2 = csr[j + 2], s3 = csr[j + 3];
        int s4 = csr[j + 4], s5 = csr[j + 5], s6 = csr[j + 6], s7 = csr[j + 7];
        if (act) {
            float v0 = bf2f(hws[(size_t)s0 * CLS + c]);
            float v1 = bf2f(hws[(size_t)s1 * CLS + c]);
            float v2 = bf2f(hws[(size_t)s2 * CLS + c]);
            float v3 = bf2f(hws[(size_t)s3 * CLS + c]);
            float v4 = bf2f(hws[(size_t)s4 * CLS + c]);
            float v5 = bf2f(hws[(size_t)s5 * CLS + c]);
            float v6 = bf2f(hws[(size_t)s6 * CLS + c]);
            float v7 = bf2f(hws[(size_t)s7 * CLS + c]);
            acc += ((v0 + v1) + (v2 + v3)) + ((v4 + v5) + (v6 + v7));
        }
    }
    for (; j < endp; ++j) {
        int s = csr[j];
        if (act) acc += bf2f(hws[(size_t)s * CLS + c]);
    }
    float raw = 0.f;
    if (act) raw = acc * dinv[wv] + b2[c];
    float m = act ? raw : -3.0e38f;
    #pragma unroll
    for (int o = 32; o > 0; o >>= 1) m = fmaxf(m, __shfl_xor(m, o));
    float ex = act ? __expf(raw - m) : 0.f;
    float ssum = ex;
    #pragma unroll
    for (int o = 32; o > 0; o >>= 1) ssum += __shfl_xor(ssum, o);
    float sq = act ? raw * raw : 0.f;
    #pragma unroll
    for (int o = 32; o > 0; o >>= 1) sq += __shfl_xor(sq, o);
    size_t base = (size_t)wv * CLS + c;
    if (act) {
        xout[base]  = raw;
        float lse = m + __logf(ssum);
        lsm[base]   = raw - lse;
        sm[base]    = ex / ssum;
        xoutb[base] = f2bf(raw);
    }
    if (c == 0) rnorm[wv] = 1.0f / fmaxf(sqrtf(sq), EPS);
}

// ------------- per-edge cosine dissimilarity + gnn_edge ---------------------
// 80B row = 5 x uint4 loads per operand (full 40 bf16 channels)
__global__ void edge_kernel(const uint_t* __restrict__ pair,
                            const float* __restrict__ ew, const ushort_t* __restrict__ xoutb,
                            const float* __restrict__ rnorm,
                            float* __restrict__ cos_out, float* __restrict__ gnn_out, int E) {
    int e = blockIdx.x * blockDim.x + threadIdx.x;
    if (e >= E) return;
    uint_t u = pair[e];
    int s = (int)(u & 0xffffu);
    int d = (int)(u >> 16);
    const uint4* a4 = (const uint4*)(xoutb + (size_t)s * CLS);   // rows are 80B = 5*16B
    const uint4* b4 = (const uint4*)(xoutb + (size_t)d * CLS);
    uint4 a0 = a4[0], a1 = a4[1], a2 = a4[2], a3 = a4[3], a4v = a4[4];
    uint4 b0 = b4[0], b1 = b4[1], b2 = b4[2], b3 = b4[3], b4v = b4[4];
    float rs = rnorm[s], rd = rnorm[d];
    float dot = dot_u4(a0, b0) + dot_u4(a1, b1) + dot_u4(a2, b2)
              + dot_u4(a3, b3) + dot_u4(a4v, b4v);
    cos_out[e] = 1.0f - dot * rs * rd;
    gnn_out[e] = (ew[e] > 0.5f) ? 1.0f : -1.0f;
}

// ---------------------------------------------------------------------------
extern "C" void kernel_launch(void* const* d_in, const int* in_sizes, int n_in,
                              void* d_out, int out_size, void* d_ws, size_t ws_size,
                              hipStream_t stream) {
    const float* x   = (const float*)d_in[0];
    const void*  ei  = d_in[1];
    const float* ew  = (const float*)d_in[2];
    const float* W1  = (const float*)d_in[3];
    const float* b1  = (const float*)d_in[4];
    const float* W2  = (const float*)d_in[5];
    const float* b2  = (const float*)d_in[6];

    const int n = in_sizes[0] / F_IN;        // 50000
    const int E = in_sizes[2];               // 1600000

    // output segments (return order)
    float* lsm  = (float*)d_out;                                   // [n*CLS]
    float* xout = lsm + (size_t)n * CLS;                           // [n*CLS]
    float* cosO = xout + (size_t)n * CLS;                          // [E]
    float* gnnO = cosO + E;                                        // [E]
    float* smO  = gnnO + E;                                        // [n*CLS]

    // workspace layout (256B aligned)
    char* w = (char*)d_ws;
    auto alloc = [&](size_t bytes) {
        char* p = w;
        w += (bytes + 255) & ~(size_t)255;
        return p;
    };
    const int NBLK  = (E + EPB - 1) / EPB;   // 196 hist/scatter blocks
    const int NBUCK = (n + 255) / 256;       // 196 buckets (dst>>8)

    uint_t*   pair   = (uint_t*)  alloc((size_t)E * 4);
    uint_t*   bkt    = (uint_t*)  alloc((size_t)E * 4);
    ushort_t* csr16  = (ushort_t*)alloc((size_t)E * 2);
    int*      ghist  = (int*)     alloc((size_t)NBLK * 256 * 4);
    int*      bbase  = (int*)     alloc(257 * 4);
    int*      rowptr = (int*)     alloc(((size_t)n + 1) * 4);
    float*    dinv   = (float*)   alloc((size_t)n * 4);
    ushort_t* xws    = (ushort_t*)alloc((size_t)n * HID * 2);
    ushort_t* hws    = (ushort_t*)alloc((size_t)n * CLS * 2);
    ushort_t* xoutb  = (ushort_t*)alloc((size_t)n * CLS * 2);
    float*    rnorm  = (float*)   alloc((size_t)n * 4);
    ushort_t* W1s    = (ushort_t*)alloc((size_t)4 * 8 * 64 * 8 * 2);   // 32 KB
    int*      flag   = (int*)     alloc(64);

    detect_kernel<<<1, 64, 0, stream>>>((const int*)ei, flag);
    convert_w1_kernel<<<8, 256, 0, stream>>>(W1, W1s);
    build_hist_kernel<<<NBLK, 256, 0, stream>>>(ei, flag, pair, ghist, E);
    scan_buckets_kernel<<<1, 256, 0, stream>>>(ghist, bbase, NBLK);
    scatter_buckets_kernel<<<NBLK, 256, 0, stream>>>(pair, ghist, bbase, bkt, E);
    bucket_csr_kernel<<<NBUCK, 256, 0, stream>>>(bkt, bbase, csr16, rowptr, dinv, n, E, NBUCK);
    gemm1_mfma_kernel<<<(n + 15) / 16, 256, 0, stream>>>(x, W1s, dinv, xws, n);
    gather1_gemm2_kernel<<<((size_t)n * 64 + 255) / 256, 256, 0, stream>>>(rowptr, csr16, xws, dinv,
                                                                           b1, W2, hws, n);
    gather2_fin_kernel<<<((size_t)n * 64 + 255) / 256, 256, 0, stream>>>(rowptr, csr16, hws, dinv, b2,
                                                                         xout, lsm, smO, xoutb, rnorm, n);
    edge_kernel<<<(E + 255) / 256, 256, 0, stream>>>(pair, ew, xoutb, rnorm, cosO, gnnO, E);
}

// Round 5
// 333.771 us; speedup vs baseline: 1.1833x; 1.1623x over previous
//
#include <hip/hip_runtime.h>
#include <hip/hip_bf16.h>

#define F_IN 256
#define HID  64
#define CLS  40
#define EPS  1e-8f
#define XS_STRIDE 264   // halfwords per LDS x-tile row: 2-way max bank aliasing (free)
#define EPB  8192       // edges per block in hist/scatter passes (256 thr x 32)

typedef unsigned short ushort_t;
typedef unsigned int   uint_t;
typedef __attribute__((ext_vector_type(8))) short bf16x8;
typedef __attribute__((ext_vector_type(4))) float f32x4;

__device__ __forceinline__ float bf2f(ushort_t u) {
    union { uint_t i; float f; } v; v.i = ((uint_t)u) << 16; return v.f;
}
__device__ __forceinline__ ushort_t f2bf(float f) {
    union { float f; uint_t i; } v; v.f = f;
    uint_t r = v.i + 0x7fff + ((v.i >> 16) & 1);          // RNE
    return (ushort_t)(r >> 16);
}
__device__ __forceinline__ float blo(uint_t p) {
    union { uint_t i; float f; } v; v.i = p << 16; return v.f;
}
__device__ __forceinline__ float bhi(uint_t p) {
    union { uint_t i; float f; } v; v.i = p & 0xffff0000u; return v.f;
}
__device__ __forceinline__ float dot_u4(uint4 a, uint4 b) {
    return blo(a.x) * blo(b.x) + bhi(a.x) * bhi(b.x)
         + blo(a.y) * blo(b.y) + bhi(a.y) * bhi(b.y)
         + blo(a.z) * blo(b.z) + bhi(a.z) * bhi(b.z)
         + blo(a.w) * blo(b.w) + bhi(a.w) * bhi(b.w);
}

// -------------------- dtype detection (int64 vs int32 edge_index) -----------
__global__ void detect_kernel(const int* __restrict__ raw, int* __restrict__ flag) {
    int c = threadIdx.x;                  // one wave
    int w = raw[2 * c + 1];               // odd int32 words
    unsigned long long b = __ballot(w != 0);
    if (c == 0) *flag = (b == 0ULL) ? 1 : 0;   // all zero -> int64 layout
}

// ---- pass 1: pair packing + per-block bucket histogram (dst>>8) ------------
// NO global atomics anywhere in the CSR build: LDS histogram + scans instead.
__global__ void build_hist_kernel(const void* __restrict__ raw, const int* __restrict__ flag,
                                  uint_t* __restrict__ pair, int* __restrict__ ghist, int E) {
    __shared__ int lhist[256];
    int tid = threadIdx.x;
    lhist[tid] = 0;
    __syncthreads();
    int base = blockIdx.x * EPB;
    if (*flag) {
        const long long* r = (const long long*)raw;
        for (int it = 0; it < EPB / 1024; ++it) {        // 4 edges/thread/iter
            int e = base + (it * 256 + tid) * 4;
            if (e + 4 <= E) {
                ulonglong2 a0 = *(const ulonglong2*)(r + e);
                ulonglong2 a1 = *(const ulonglong2*)(r + e + 2);
                ulonglong2 b0 = *(const ulonglong2*)(r + E + e);
                ulonglong2 b1 = *(const ulonglong2*)(r + E + e + 2);
                uint_t d0 = (uint_t)b0.x, d1 = (uint_t)b0.y;
                uint_t d2 = (uint_t)b1.x, d3 = (uint_t)b1.y;
                uint4 p;
                p.x = (d0 << 16) | (uint_t)a0.x;
                p.y = (d1 << 16) | (uint_t)a0.y;
                p.z = (d2 << 16) | (uint_t)a1.x;
                p.w = (d3 << 16) | (uint_t)a1.y;
                *(uint4*)(pair + e) = p;
                atomicAdd(&lhist[d0 >> 8], 1);
                atomicAdd(&lhist[d1 >> 8], 1);
                atomicAdd(&lhist[d2 >> 8], 1);
                atomicAdd(&lhist[d3 >> 8], 1);
            } else {
                for (int k = 0; k < 4; ++k) {
                    int ee = e + k;
                    if (ee < E) {
                        uint_t s = (uint_t)r[ee];
                        uint_t d = (uint_t)r[E + ee];
                        pair[ee] = (d << 16) | s;
                        atomicAdd(&lhist[d >> 8], 1);
                    }
                }
            }
        }
    } else {
        const int* r = (const int*)raw;
        for (int it = 0; it < EPB / 1024; ++it) {        // 4 edges/thread/iter
            int e = base + (it * 256 + tid) * 4;
            if (e + 4 <= E) {
                int4 a = *(const int4*)(r + e);
                int4 b = *(const int4*)(r + E + e);
                uint_t d0 = (uint_t)b.x, d1 = (uint_t)b.y;
                uint_t d2 = (uint_t)b.z, d3 = (uint_t)b.w;
                uint4 p;
                p.x = (d0 << 16) | (uint_t)a.x;
                p.y = (d1 << 16) | (uint_t)a.y;
                p.z = (d2 << 16) | (uint_t)a.z;
                p.w = (d3 << 16) | (uint_t)a.w;
                *(uint4*)(pair + e) = p;
                atomicAdd(&lhist[d0 >> 8], 1);
                atomicAdd(&lhist[d1 >> 8], 1);
                atomicAdd(&lhist[d2 >> 8], 1);
                atomicAdd(&lhist[d3 >> 8], 1);
            } else {
                for (int k = 0; k < 4; ++k) {
                    int ee = e + k;
                    if (ee < E) {
                        uint_t s = (uint_t)r[ee];
                        uint_t d = (uint_t)r[E + ee];
                        pair[ee] = (d << 16) | s;
                        atomicAdd(&lhist[d >> 8], 1);
                    }
                }
            }
        }
    }
    __syncthreads();
    ghist[blockIdx.x * 256 + tid] = lhist[tid];
}

// ---- pass 2a: PARALLEL column scan — one wave per bucket -------------------
// Replaces the serial single-block scan (196-deep dependent latency chain that
// idled 255 CUs for ~40us). 4 batches of 64 values, wave-scan via shfl_up.
__global__ void scan_cols_kernel(int* __restrict__ ghist, int* __restrict__ btot,
                                 int NBLK) {
    int k    = blockIdx.x;                 // bucket 0..255
    int lane = threadIdx.x;                // 0..63
    int carry = 0;
    for (int b0 = 0; b0 < NBLK; b0 += 64) {
        int b = b0 + lane;
        int v = (b < NBLK) ? ghist[b * 256 + k] : 0;
        int x = v;
        #pragma unroll
        for (int o = 1; o < 64; o <<= 1) {
            int t = __shfl_up(x, o);
            if (lane >= o) x += t;
        }
        if (b < NBLK) ghist[b * 256 + k] = carry + x - v;   // exclusive offset
        carry += __shfl(x, 63);            // batch total
    }
    if (lane == 0) btot[k] = carry;        // bucket total
}

// ---- pass 2b (1 block): exclusive scan of bucket totals -> bucket bases ----
__global__ void scan_base_kernel(const int* __restrict__ btot, int* __restrict__ bbase) {
    __shared__ int s[256];
    int k = threadIdx.x;
    int v = btot[k];
    int x = v;
    s[k] = x;
    __syncthreads();
    #pragma unroll
    for (int o = 1; o < 256; o <<= 1) {
        int t = (k >= o) ? s[k - o] : 0;
        __syncthreads();
        x += t;
        s[k] = x;
        __syncthreads();
    }
    bbase[k] = x - v;                      // exclusive bucket base
    if (k == 255) bbase[256] = x;          // == E
}

// ---- pass 3: scatter edges into bucket regions (LDS cursors only) ----------
// block b's targets in bucket k are the exclusive range [off(b,k), off(b,k)+cnt):
// 4B stores merge in write-back L2 -> ~no write amplification.
__global__ void scatter_buckets_kernel(const uint_t* __restrict__ pair,
                                       const int* __restrict__ ghist,
                                       const int* __restrict__ bbase,
                                       uint_t* __restrict__ bkt, int E) {
    __shared__ int cursor[256];
    int tid = threadIdx.x;
    cursor[tid] = ghist[blockIdx.x * 256 + tid] + bbase[tid];
    __syncthreads();
    int base = blockIdx.x * EPB;
    for (int it = 0; it < EPB / 256; ++it) {
        int e = base + it * 256 + tid;
        if (e < E) {
            uint_t u = pair[e];
            int pos = atomicAdd(&cursor[u >> 24], 1);   // LDS atomic, returns rank
            bkt[pos] = u;
        }
    }
}

// ---- pass 4: one block per bucket -> deg/rowptr/dinv + sorted csr16 --------
// bucket k holds ALL edges of nodes [k*256,(k+1)*256): LDS histogram over
// dst&255 IS the exact degree; LDS scan gives rowptr; LDS cursors place src.
// Bucket segment (~33 KB) is read twice; L2-resident after pass A.
__global__ void bucket_csr_kernel(const uint_t* __restrict__ bkt,
                                  const int* __restrict__ bbase,
                                  ushort_t* __restrict__ csr, int* __restrict__ rowptr,
                                  float* __restrict__ dinv, int n, int E, int NBUCK) {
    __shared__ int lhist[256];
    __shared__ int lscan[256];
    __shared__ int cursor[256];
    int tid = threadIdx.x;
    int kb  = blockIdx.x;
    int base = bbase[kb];
    int cnt  = bbase[kb + 1] - base;
    lhist[tid] = 0;
    __syncthreads();
    for (int i = tid; i < cnt; i += 256) {            // pass A: exact degrees
        uint_t u = bkt[base + i];
        atomicAdd(&lhist[(u >> 16) & 255], 1);
    }
    __syncthreads();
    int v = lhist[tid];                        // degree of node kb*256+tid (no self-loop)
    int x = v;
    lscan[tid] = x;
    __syncthreads();
    #pragma unroll
    for (int o = 1; o < 256; o <<= 1) {
        int t = (tid >= o) ? lscan[tid - o] : 0;
        __syncthreads();
        x += t;
        lscan[tid] = x;
        __syncthreads();
    }
    int excl = x - v;                          // exclusive scan within bucket
    int node = kb * 256 + tid;
    if (node < n) {
        rowptr[node] = base + excl;
        dinv[node]   = rsqrtf((float)(v + 1)); // +1 self-loop
    }
    cursor[tid] = base + excl;
    if (kb == NBUCK - 1 && tid == 0) rowptr[n] = E;
    __syncthreads();
    for (int i = tid; i < cnt; i += 256) {            // pass B: place src
        uint_t u = bkt[base + i];                     // L2 hit (just touched)
        int pos = atomicAdd(&cursor[(u >> 16) & 255], 1);   // LDS atomic
        csr[pos] = (ushort_t)(u & 0xffffu);    // 2B scatter, block-local region
    }
}

// ---- W1 -> bf16, pre-swizzled into MFMA B-fragment order -------------------
// frag elem j of (nt, kk, lane): W1[kk*32 + (lane>>4)*8 + j][nt*16 + (lane&15)]
// stored contiguously at W1s[(((nt*8)+kk)*64 + lane)*8 + j]
__global__ void convert_w1_kernel(const float* __restrict__ W1, ushort_t* __restrict__ W1s) {
    int t = blockIdx.x * blockDim.x + threadIdx.x;   // 2048 triples
    if (t >= 4 * 8 * 64) return;
    int lane = t & 63;
    int kk   = (t >> 6) & 7;
    int nt   = t >> 9;
    int col  = nt * 16 + (lane & 15);
    int k0   = kk * 32 + (lane >> 4) * 8;
    ushort_t v[8];
    #pragma unroll
    for (int j = 0; j < 8; ++j) v[j] = f2bf(W1[(size_t)(k0 + j) * HID + col]);
    uint4 p;
    p.x = (uint_t)v[0] | ((uint_t)v[1] << 16);
    p.y = (uint_t)v[2] | ((uint_t)v[3] << 16);
    p.z = (uint_t)v[4] | ((uint_t)v[5] << 16);
    p.w = (uint_t)v[6] | ((uint_t)v[7] << 16);
    *(uint4*)(W1s + (size_t)t * 8) = p;
}

// ------- layer 1 GEMM on MFMA: xws = bf16((x @ W1) * dinv[node]) ------------
// block = 256 threads = 4 waves; 16 nodes/block; wave w owns N-tile w (16 ch)
__global__ void gemm1_mfma_kernel(const float* __restrict__ x,
                                  const ushort_t* __restrict__ W1s,
                                  const float* __restrict__ dinv,
                                  ushort_t* __restrict__ xws, int n) {
    __shared__ ushort_t xs[16 * XS_STRIDE];           // 8448 B bf16 x-tile
    int node0 = blockIdx.x * 16;
    int tid = threadIdx.x;
    for (int i = tid; i < 16 * 64; i += 256) {        // stage x tile -> bf16 LDS
        int r  = i >> 6;
        int c4 = (i & 63) << 2;
        int node = node0 + r;
        float4 v = (node < n) ? *(const float4*)(x + (size_t)node * F_IN + c4)
                              : make_float4(0.f, 0.f, 0.f, 0.f);
        ushort4 b;
        b.x = f2bf(v.x); b.y = f2bf(v.y); b.z = f2bf(v.z); b.w = f2bf(v.w);
        *(ushort4*)(&xs[r * XS_STRIDE + c4]) = b;     // 8B-aligned ds_write_b64
    }
    __syncthreads();
    int wave = tid >> 6;                              // N-tile index 0..3
    int lane = tid & 63;
    int m    = lane & 15;
    int q    = lane >> 4;
    f32x4 acc = {0.f, 0.f, 0.f, 0.f};
    #pragma unroll
    for (int kk = 0; kk < 8; ++kk) {                  // K = 8 x 32
        bf16x8 a = *(const bf16x8*)(&xs[m * XS_STRIDE + kk * 32 + q * 8]);
        bf16x8 b = *(const bf16x8*)(W1s + (((size_t)wave * 8 + kk) * 64 + lane) * 8);
        acc = __builtin_amdgcn_mfma_f32_16x16x32_bf16(a, b, acc, 0, 0, 0);
    }
    int ch = wave * 16 + m;                           // C/D: col=lane&15, row=q*4+r
    #pragma unroll
    for (int r = 0; r < 4; ++r) {
        int node = node0 + q * 4 + r;
        if (node < n)
            xws[(size_t)node * HID + ch] = f2bf(acc[r] * dinv[node]);
    }
}

// ---- fused: gather1 (h = relu(dinv*(sum)+b1)) + gemm2 (hws = h@W2 * dinv) --
// one wave per node; 16 outstanding row loads (L2-latency-bound -> more ILP)
__global__ void gather1_gemm2_kernel(const int* __restrict__ rowptr,
                                     const ushort_t* __restrict__ csr,
                                     const ushort_t* __restrict__ xws,
                                     const float* __restrict__ dinv,
                                     const float* __restrict__ b1,
                                     const float* __restrict__ W2,
                                     ushort_t* __restrict__ hws, int n) {
    __shared__ float hbuf[4][72];
    int wave = threadIdx.x >> 6;
    int c    = threadIdx.x & 63;
    int wv   = (blockIdx.x * blockDim.x + threadIdx.x) >> 6;
    bool active = wv < n;
    int beg = 0, endp = 0;
    float acc = 0.f, di = 0.f;
    if (active) {
        beg = rowptr[wv]; endp = rowptr[wv + 1];
        di  = dinv[wv];
        acc = bf2f(xws[(size_t)wv * HID + c]);        // self-loop term
    }
    int j = beg;
    for (; j + 16 <= endp; j += 16) {                 // 16 outstanding row loads
        int ss[16];
        #pragma unroll
        for (int k = 0; k < 16; ++k) ss[k] = csr[j + k];
        float vv[16];
        #pragma unroll
        for (int k = 0; k < 16; ++k) vv[k] = bf2f(xws[(size_t)ss[k] * HID + c]);
        float s0 = ((vv[0] + vv[1]) + (vv[2] + vv[3])) + ((vv[4] + vv[5]) + (vv[6] + vv[7]));
        float s1 = ((vv[8] + vv[9]) + (vv[10] + vv[11])) + ((vv[12] + vv[13]) + (vv[14] + vv[15]));
        acc += s0 + s1;
    }
    for (; j + 4 <= endp; j += 4) {
        int s0 = csr[j], s1 = csr[j + 1], s2 = csr[j + 2], s3 = csr[j + 3];
        float v0 = bf2f(xws[(size_t)s0 * HID + c]);
        float v1 = bf2f(xws[(size_t)s1 * HID + c]);
        float v2 = bf2f(xws[(size_t)s2 * HID + c]);
        float v3 = bf2f(xws[(size_t)s3 * HID + c]);
        acc += (v0 + v1) + (v2 + v3);
    }
    for (; j < endp; ++j) acc += bf2f(xws[(size_t)csr[j] * HID + c]);
    float hv = active ? fmaxf(acc * di + b1[c], 0.f) : 0.f;
    hbuf[wave][c] = hv;
    __syncthreads();
    if (active && c < CLS) {
        float o = 0.f;
        const float* hr = hbuf[wave];
        #pragma unroll 8
        for (int k = 0; k < HID; ++k) o += hr[k] * W2[k * CLS + c];
        hws[(size_t)wv * CLS + c] = f2bf(o * di);
    }
}

// ---------- layer 2 gather fused with finalize ------------------------------
__global__ void gather2_fin_kernel(const int* __restrict__ rowptr,
                                   const ushort_t* __restrict__ csr,
                                   const ushort_t* __restrict__ hws,
                                   const float* __restrict__ dinv,
                                   const float* __restrict__ b2,
                                   float* __restrict__ xout, float* __restrict__ lsm,
                                   float* __restrict__ sm, ushort_t* __restrict__ xoutb,
                                   float* __restrict__ rnorm, int n) {
    int wv = (blockIdx.x * blockDim.x + threadIdx.x) >> 6;
    int c  = threadIdx.x & 63;
    if (wv >= n) return;
    int beg = rowptr[wv], endp = rowptr[wv + 1];
    bool act = c < CLS;
    float acc = 0.f;
    if (act) acc = bf2f(hws[(size_t)wv * CLS + c]);   // self-loop term
    int j = beg;
    for (; j + 16 <= endp; j += 16) {                 // 16 outstanding row loads
        int ss[16];
        #pragma unroll
        for (int k = 0; k < 16; ++k) ss[k] = csr[j + k];
        if (act) {
            float vv[16];
            #pragma unroll
            for (int k = 0; k < 16; ++k) vv[k] = bf2f(hws[(size_t)ss[k] * CLS + c]);
            float s0 = ((vv[0] + vv[1]) + (vv[2] + vv[3])) + ((vv[4] + vv[5]) + (vv[6] + vv[7]));
            float s1 = ((vv[8] + vv[9]) + (vv[10] + vv[11])) + ((vv[12] + vv[13]) + (vv[14] + vv[15]));
            acc += s0 + s1;
        }
    }
    for (; j + 4 <= endp; j += 4) {
        int s0 = csr[j], s1 = csr[j + 1], s2 = csr[j + 2], s3 = csr[j + 3];
        if (act) {
            float v0 = bf2f(hws[(size_t)s0 * CLS + c]);
            float v1 = bf2f(hws[(size_t)s1 * CLS + c]);
            float v2 = bf2f(hws[(size_t)s2 * CLS + c]);
            float v3 = bf2f(hws[(size_t)s3 * CLS + c]);
            acc += (v0 + v1) + (v2 + v3);
        }
    }
    for (; j < endp; ++j) {
        int s = csr[j];
        if (act) acc += bf2f(hws[(size_t)s * CLS + c]);
    }
    float raw = 0.f;
    if (act) raw = acc * dinv[wv] + b2[c];
    float m = act ? raw : -3.0e38f;
    #pragma unroll
    for (int o = 32; o > 0; o >>= 1) m = fmaxf(m, __shfl_xor(m, o));
    float ex = act ? __expf(raw - m) : 0.f;
    float ssum = ex;
    #pragma unroll
    for (int o = 32; o > 0; o >>= 1) ssum += __shfl_xor(ssum, o);
    float sq = act ? raw * raw : 0.f;
    #pragma unroll
    for (int o = 32; o > 0; o >>= 1) sq += __shfl_xor(sq, o);
    size_t base = (size_t)wv * CLS + c;
    if (act) {
        xout[base]  = raw;
        float lse = m + __logf(ssum);
        lsm[base]   = raw - lse;
        sm[base]    = ex / ssum;
        xoutb[base] = f2bf(raw);
    }
    if (c == 0) rnorm[wv] = 1.0f / fmaxf(sqrtf(sq), EPS);
}

// ------------- per-edge cosine dissimilarity + gnn_edge ---------------------
// 80B row = 5 x uint4 loads per operand (full 40 bf16 channels)
__global__ void edge_kernel(const uint_t* __restrict__ pair,
                            const float* __restrict__ ew, const ushort_t* __restrict__ xoutb,
                            const float* __restrict__ rnorm,
                            float* __restrict__ cos_out, float* __restrict__ gnn_out, int E) {
    int e = blockIdx.x * blockDim.x + threadIdx.x;
    if (e >= E) return;
    uint_t u = pair[e];
    int s = (int)(u & 0xffffu);
    int d = (int)(u >> 16);
    const uint4* a4 = (const uint4*)(xoutb + (size_t)s * CLS);   // rows are 80B = 5*16B
    const uint4* b4 = (const uint4*)(xoutb + (size_t)d * CLS);
    uint4 a0 = a4[0], a1 = a4[1], a2 = a4[2], a3 = a4[3], a4v = a4[4];
    uint4 b0 = b4[0], b1 = b4[1], b2 = b4[2], b3 = b4[3], b4v = b4[4];
    float rs = rnorm[s], rd = rnorm[d];
    float dot = dot_u4(a0, b0) + dot_u4(a1, b1) + dot_u4(a2, b2)
              + dot_u4(a3, b3) + dot_u4(a4v, b4v);
    cos_out[e] = 1.0f - dot * rs * rd;
    gnn_out[e] = (ew[e] > 0.5f) ? 1.0f : -1.0f;
}

// ---------------------------------------------------------------------------
extern "C" void kernel_launch(void* const* d_in, const int* in_sizes, int n_in,
                              void* d_out, int out_size, void* d_ws, size_t ws_size,
                              hipStream_t stream) {
    const float* x   = (const float*)d_in[0];
    const void*  ei  = d_in[1];
    const float* ew  = (const float*)d_in[2];
    const float* W1  = (const float*)d_in[3];
    const float* b1  = (const float*)d_in[4];
    const float* W2  = (const float*)d_in[5];
    const float* b2  = (const float*)d_in[6];

    const int n = in_sizes[0] / F_IN;        // 50000
    const int E = in_sizes[2];               // 1600000

    // output segments (return order)
    float* lsm  = (float*)d_out;                                   // [n*CLS]
    float* xout = lsm + (size_t)n * CLS;                           // [n*CLS]
    float* cosO = xout + (size_t)n * CLS;                          // [E]
    float* gnnO = cosO + E;                                        // [E]
    float* smO  = gnnO + E;                                        // [n*CLS]

    // workspace layout (256B aligned)
    char* w = (char*)d_ws;
    auto alloc = [&](size_t bytes) {
        char* p = w;
        w += (bytes + 255) & ~(size_t)255;
        return p;
    };
    const int NBLK  = (E + EPB - 1) / EPB;   // 196 hist/scatter blocks
    const int NBUCK = (n + 255) / 256;       // 196 buckets (dst>>8)

    uint_t*   pair   = (uint_t*)  alloc((size_t)E * 4);
    uint_t*   bkt    = (uint_t*)  alloc((size_t)E * 4);
    ushort_t* csr16  = (ushort_t*)alloc((size_t)E * 2);
    int*      ghist  = (int*)     alloc((size_t)NBLK * 256 * 4);
    int*      btot   = (int*)     alloc(256 * 4);
    int*      bbase  = (int*)     alloc(257 * 4);
    int*      rowptr = (int*)     alloc(((size_t)n + 1) * 4);
    float*    dinv   = (float*)   alloc((size_t)n * 4);
    ushort_t* xws    = (ushort_t*)alloc((size_t)n * HID * 2);
    ushort_t* hws    = (ushort_t*)alloc((size_t)n * CLS * 2);
    ushort_t* xoutb  = (ushort_t*)alloc((size_t)n * CLS * 2);
    float*    rnorm  = (float*)   alloc((size_t)n * 4);
    ushort_t* W1s    = (ushort_t*)alloc((size_t)4 * 8 * 64 * 8 * 2);   // 32 KB
    int*      flag   = (int*)     alloc(64);

    detect_kernel<<<1, 64, 0, stream>>>((const int*)ei, flag);
    convert_w1_kernel<<<8, 256, 0, stream>>>(W1, W1s);
    build_hist_kernel<<<NBLK, 256, 0, stream>>>(ei, flag, pair, ghist, E);
    scan_cols_kernel<<<256, 64, 0, stream>>>(ghist, btot, NBLK);
    scan_base_kernel<<<1, 256, 0, stream>>>(btot, bbase);
    scatter_buckets_kernel<<<NBLK, 256, 0, stream>>>(pair, ghist, bbase, bkt, E);
    bucket_csr_kernel<<<NBUCK, 256, 0, stream>>>(bkt, bbase, csr16, rowptr, dinv, n, E, NBUCK);
    gemm1_mfma_kernel<<<(n + 15) / 16, 256, 0, stream>>>(x, W1s, dinv, xws, n);
    gather1_gemm2_kernel<<<((size_t)n * 64 + 255) / 256, 256, 0, stream>>>(rowptr, csr16, xws, dinv,
                                                                           b1, W2, hws, n);
    gather2_fin_kernel<<<((size_t)n * 64 + 255) / 256, 256, 0, stream>>>(rowptr, csr16, hws, dinv, b2,
                                                                         xout, lsm, smO, xoutb, rnorm, n);
    edge_kernel<<<(E + 255) / 256, 256, 0, stream>>>(pair, ew, xoutb, rnorm, cosO, gnnO, E);
}